// Round 1
// baseline (59.713 us; speedup 1.0000x reference)
//
#include <hip/hip_runtime.h>

// FrequencyLayer: 8x8 patch DCT-II, keep 2x2 low corner and flipped 2x2 high corner.
// x: (64,3,512,512) f32. Outputs (each): (64,64,64,3,2,2) f32, concatenated low||high.
//
// Output indexing derivation (the reference reshape MIXES p,q,c):
//   m = p*192 + q*3 + c   (memory-linear index over (p,q,c))
//   r = m>>12, s = (m>>6)&63, t = m&63          (relabel as (C,PH,PW))
//   out slot = (b*12288 + s*192 + t*3 + r)*4 + k*2 + l
// low stores d[k][l], k,l in {0,1}; high stores d[7-k][7-l].

__global__ __launch_bounds__(256) void freq_dct_kernel(
    const float* __restrict__ x, float* __restrict__ out_low, float* __restrict__ out_high)
{
    // DCT-II rows 0,1,6,7 (scaled): DR[0]=row0, DR[1]=row1, DR[2]=row6, DR[3]=row7
    const float DR[4][8] = {
        { 0.35355339059327373f, 0.35355339059327373f, 0.35355339059327373f, 0.35355339059327373f,
          0.35355339059327373f, 0.35355339059327373f, 0.35355339059327373f, 0.35355339059327373f },
        { 0.49039264020161522f, 0.41573480615127262f, 0.27778511650980109f, 0.09754516100806412f,
         -0.09754516100806412f,-0.27778511650980109f,-0.41573480615127262f,-0.49039264020161522f },
        { 0.19134171618254489f,-0.46193976625564337f, 0.46193976625564337f,-0.19134171618254489f,
         -0.19134171618254489f, 0.46193976625564337f,-0.46193976625564337f, 0.19134171618254489f },
        { 0.09754516100806412f,-0.27778511650980109f, 0.41573480615127262f,-0.49039264020161522f,
          0.49039264020161522f,-0.41573480615127262f, 0.27778511650980109f,-0.09754516100806412f }
    };

    const int tid = blockIdx.x * 256 + threadIdx.x;   // one thread per patch
    const int q  = tid & 63;          // patch col (lane) -> coalesced reads
    const int r1 = tid >> 6;
    const int p  = r1 & 63;           // patch row
    const int r2 = r1 >> 6;           // in [0, 192)
    const int c  = r2 % 3;
    const int b  = r2 / 3;

    const float* src = x + ((size_t)(b*3 + c) * 512 + (size_t)p * 8) * 512 + (size_t)q * 8;

    // Stage 1: t[k][j] = sum_i DR[k][i] * patch[i][j]
    float t[4][8];
    #pragma unroll
    for (int k = 0; k < 4; ++k)
        #pragma unroll
        for (int j = 0; j < 8; ++j) t[k][j] = 0.0f;

    #pragma unroll
    for (int i = 0; i < 8; ++i) {
        const float4 a0 = *reinterpret_cast<const float4*>(src + (size_t)i * 512);
        const float4 a1 = *reinterpret_cast<const float4*>(src + (size_t)i * 512 + 4);
        const float row[8] = { a0.x, a0.y, a0.z, a0.w, a1.x, a1.y, a1.z, a1.w };
        #pragma unroll
        for (int k = 0; k < 4; ++k) {
            const float dk = DR[k][i];
            #pragma unroll
            for (int j = 0; j < 8; ++j) t[k][j] = fmaf(dk, row[j], t[k][j]);
        }
    }

    // Stage 2: d[k][l] = sum_j t[k][j] * DR_l[j]
    float lv[4], hv[4];
    #pragma unroll
    for (int a = 0; a < 2; ++a) {
        #pragma unroll
        for (int l = 0; l < 2; ++l) {
            float accL = 0.0f, accH = 0.0f;
            #pragma unroll
            for (int j = 0; j < 8; ++j) {
                accL = fmaf(t[a][j],     DR[l][j],     accL);   // d[a][l]
                accH = fmaf(t[3 - a][j], DR[3 - l][j], accH);   // d[7-a][7-l]
            }
            lv[a*2 + l] = accL;
            hv[a*2 + l] = accH;
        }
    }

    // Output slot per the reshape-mixing derivation
    const int m  = p * 192 + q * 3 + c;
    const int rr = m >> 12;
    const int ss = (m >> 6) & 63;
    const int tt = m & 63;
    const size_t off = ((size_t)b * 12288 + (size_t)(ss * 192 + tt * 3 + rr)) * 4;

    *reinterpret_cast<float4*>(out_low  + off) = make_float4(lv[0], lv[1], lv[2], lv[3]);
    *reinterpret_cast<float4*>(out_high + off) = make_float4(hv[0], hv[1], hv[2], hv[3]);
}

extern "C" void kernel_launch(void* const* d_in, const int* in_sizes, int n_in,
                              void* d_out, int out_size, void* d_ws, size_t ws_size,
                              hipStream_t stream) {
    const float* x = (const float*)d_in[0];
    float* out  = (float*)d_out;
    float* low  = out;
    float* high = out + 3145728;   // 64*64*64*3*2*2

    // 64*3*64*64 patches = 786432 threads = 3072 blocks of 256
    hipLaunchKernelGGL(freq_dct_kernel, dim3(3072), dim3(256), 0, stream,
                       x, low, high);
}

// Round 2
// 43.323 us; speedup vs baseline: 1.3783x; 1.3783x over previous
//
#include <hip/hip_runtime.h>

// FrequencyLayer: 8x8 patch DCT-II, keep 2x2 low corner and flipped 2x2 high corner.
// x: (64,3,512,512) f32. Outputs: low||high, each (64,64,64,3,2,2) f32.
//
// Output linear index: b*49152 + ss*768 + tt*12 + rr*4 + k*2 + l
// where the source patch is m = rr*4096 + ss*64 + tt, and m = p*192 + q*3 + c
// (p = patch row, q = patch col, c = channel).
//
// Block = (b, ss): 192 threads, one patch each (rr = idx>>6, tt = idx&63).
// Results staged in LDS in output order -> two contiguous 3 KB float4 bursts.

__global__ __launch_bounds__(192) void freq_dct_kernel(
    const float* __restrict__ x, float* __restrict__ out_low, float* __restrict__ out_high)
{
    // DCT-II rows 0,1,6,7 (scaled): DR[0]=row0, DR[1]=row1, DR[2]=row6, DR[3]=row7
    const float DR[4][8] = {
        { 0.35355339059327373f, 0.35355339059327373f, 0.35355339059327373f, 0.35355339059327373f,
          0.35355339059327373f, 0.35355339059327373f, 0.35355339059327373f, 0.35355339059327373f },
        { 0.49039264020161522f, 0.41573480615127262f, 0.27778511650980109f, 0.09754516100806412f,
         -0.09754516100806412f,-0.27778511650980109f,-0.41573480615127262f,-0.49039264020161522f },
        { 0.19134171618254489f,-0.46193976625564337f, 0.46193976625564337f,-0.19134171618254489f,
         -0.19134171618254489f, 0.46193976625564337f,-0.46193976625564337f, 0.19134171618254489f },
        { 0.09754516100806412f,-0.27778511650980109f, 0.41573480615127262f,-0.49039264020161522f,
          0.49039264020161522f,-0.41573480615127262f, 0.27778511650980109f,-0.09754516100806412f }
    };

    __shared__ float lds_lo[768];
    __shared__ float lds_hi[768];

    const int bss = blockIdx.x;        // b*64 + ss
    const int b   = bss >> 6;
    const int ss  = bss & 63;
    const int idx = threadIdx.x;       // 0..191
    const int rr  = idx >> 6;          // wave id (0..2)
    const int tt  = idx & 63;          // lane

    // Patch for this output slot
    const int m   = rr * 4096 + ss * 64 + tt;
    const int p   = m / 192;                 // compile-time magic mul
    const int rem = m - p * 192;
    const int q   = rem / 3;
    const int c   = rem - q * 3;

    const float* src = x + ((size_t)(b * 3 + c) * 512 + (size_t)p * 8) * 512 + (size_t)q * 8;

    // Stage 1: t[k][j] = sum_i DR[k][i] * patch[i][j]
    float t[4][8];
    #pragma unroll
    for (int k = 0; k < 4; ++k)
        #pragma unroll
        for (int j = 0; j < 8; ++j) t[k][j] = 0.0f;

    #pragma unroll
    for (int i = 0; i < 8; ++i) {
        const float4 a0 = *reinterpret_cast<const float4*>(src + (size_t)i * 512);
        const float4 a1 = *reinterpret_cast<const float4*>(src + (size_t)i * 512 + 4);
        const float row[8] = { a0.x, a0.y, a0.z, a0.w, a1.x, a1.y, a1.z, a1.w };
        #pragma unroll
        for (int k = 0; k < 4; ++k) {
            const float dk = DR[k][i];
            #pragma unroll
            for (int j = 0; j < 8; ++j) t[k][j] = fmaf(dk, row[j], t[k][j]);
        }
    }

    // Stage 2: d[k][l] = sum_j t[k][j] * DR_l[j];  low = d[a][l], high = d[7-a][7-l]
    float lv[4], hv[4];
    #pragma unroll
    for (int a = 0; a < 2; ++a) {
        #pragma unroll
        for (int l = 0; l < 2; ++l) {
            float accL = 0.0f, accH = 0.0f;
            #pragma unroll
            for (int j = 0; j < 8; ++j) {
                accL = fmaf(t[a][j],     DR[l][j],     accL);
                accH = fmaf(t[3 - a][j], DR[3 - l][j], accH);
            }
            lv[a * 2 + l] = accL;
            hv[a * 2 + l] = accH;
        }
    }

    // Stage results in LDS in output order: [tt][rr][e]
    const int base = tt * 12 + rr * 4;    // 16-B aligned
    *reinterpret_cast<float4*>(&lds_lo[base]) = make_float4(lv[0], lv[1], lv[2], lv[3]);
    *reinterpret_cast<float4*>(&lds_hi[base]) = make_float4(hv[0], hv[1], hv[2], hv[3]);
    __syncthreads();

    // Cooperative contiguous write: 192 threads x float4 = 3 KB per output per block
    const size_t off = (size_t)bss * 768 + (size_t)idx * 4;
    const float4 lo4 = reinterpret_cast<const float4*>(lds_lo)[idx];
    const float4 hi4 = reinterpret_cast<const float4*>(lds_hi)[idx];
    *reinterpret_cast<float4*>(out_low  + off) = lo4;
    *reinterpret_cast<float4*>(out_high + off) = hi4;
}

extern "C" void kernel_launch(void* const* d_in, const int* in_sizes, int n_in,
                              void* d_out, int out_size, void* d_ws, size_t ws_size,
                              hipStream_t stream) {
    const float* x = (const float*)d_in[0];
    float* out  = (float*)d_out;
    float* low  = out;
    float* high = out + 3145728;   // 64*64*64*3*2*2

    // 64 b * 64 ss = 4096 blocks, 192 threads each (one patch per thread)
    hipLaunchKernelGGL(freq_dct_kernel, dim3(4096), dim3(192), 0, stream,
                       x, low, high);
}